// Round 8
// baseline (4632.102 us; speedup 1.0000x reference)
//
#include <hip/hip_runtime.h>

#define TT 512
#define BB 256
#define II 128
#define HH 256
#define RS 260   // LDS tile row stride, shorts (130 dwords == 2 mod 32 -> conflict-free)
#define RSQ 65   // row stride in u64

typedef __attribute__((ext_vector_type(8))) short short8;
typedef __attribute__((ext_vector_type(4))) float floatx4;
typedef __attribute__((ext_vector_type(4))) float fvec4;
typedef unsigned long long u64;

// ws layout: h1g u32[2][BB][HH/2] | h2g same | wb bf16 | xb bf16 | cnt u32[1024]
#define HBUF_U32 (2 * BB * (HH / 2))
#define HPAR_Q (BB * HH / 4)  // u64 per parity = 16384
#define OFF_WIH0 0
#define OFF_WHH0 (OFF_WIH0 + 3 * HH * II)
#define OFF_WIH1 (OFF_WHH0 + 3 * HH * HH)
#define OFF_WHH1 (OFF_WIH1 + 3 * HH * HH)
#define W_TOTAL (OFF_WHH1 + 3 * HH * HH)
#define XB_ELEMS ((size_t)TT * BB * II)

__device__ __forceinline__ short f2bf(float f) {
  unsigned u = __builtin_bit_cast(unsigned, f);
  u = u + 0x7fffu + ((u >> 16) & 1u);
  return (short)(u >> 16);
}
__device__ __forceinline__ float fast_sigmoid(float x) {
  return __fdividef(1.0f, 1.0f + __expf(-x));
}
__device__ __forceinline__ float fast_tanh(float x) {
  return 1.0f - __fdividef(2.0f, 1.0f + __expf(2.0f * x));
}
__device__ __forceinline__ short8 cvt8(const float* __restrict__ p) {
  fvec4 lo = *(const fvec4*)p;
  fvec4 hi = *(const fvec4*)(p + 4);
  short8 r;
  r[0] = f2bf(lo[0]); r[1] = f2bf(lo[1]); r[2] = f2bf(lo[2]); r[3] = f2bf(lo[3]);
  r[4] = f2bf(hi[0]); r[5] = f2bf(hi[1]); r[6] = f2bf(hi[2]); r[7] = f2bf(hi[3]);
  return r;
}
__device__ __forceinline__ u64 ld64(const u64* p) {
  return __hip_atomic_load(p, __ATOMIC_RELAXED, __HIP_MEMORY_SCOPE_AGENT);
}
__device__ __forceinline__ void st64(u64* p, u64 v) {
  __hip_atomic_store(p, v, __ATOMIC_RELAXED, __HIP_MEMORY_SCOPE_AGENT);
}
__device__ __forceinline__ void st32a(unsigned* p, unsigned v) {
  __hip_atomic_store(p, v, __ATOMIC_RELAXED, __HIP_MEMORY_SCOPE_AGENT);
}
__device__ __forceinline__ void spin_ge(const unsigned* c, unsigned tgt) {
  int g = 0;
  while (__hip_atomic_load(c, __ATOMIC_RELAXED, __HIP_MEMORY_SCOPE_AGENT) < tgt &&
         g < (1 << 22))
    ++g;
}
__device__ __forceinline__ void drain_then(void) {
  __atomic_signal_fence(__ATOMIC_SEQ_CST);
  __builtin_amdgcn_s_waitcnt(0);
  __atomic_signal_fence(__ATOMIC_SEQ_CST);
}

__global__ __launch_bounds__(256) void cvt_weights(
    const float* __restrict__ w0, const float* __restrict__ w1,
    const float* __restrict__ w2, const float* __restrict__ w3,
    short* __restrict__ out) {
  int i = blockIdx.x * 256 + threadIdx.x;
  if (i >= W_TOTAL) return;
  float v;
  if (i < OFF_WHH0)      v = w0[i - OFF_WIH0];
  else if (i < OFF_WIH1) v = w1[i - OFF_WHH0];
  else if (i < OFF_WHH1) v = w2[i - OFF_WIH1];
  else                   v = w3[i - OFF_WHH1];
  out[i] = f2bf(v);
}

__global__ __launch_bounds__(256) void cvt_x(const float* __restrict__ x,
                                             short* __restrict__ xb) {
  size_t i = ((size_t)blockIdx.x * 256 + threadIdx.x) * 8;
  if (i >= XB_ELEMS) return;
#pragma unroll
  for (int k = 0; k < 8; ++k) xb[i + k] = f2bf(x[i + k]);
}

__global__ __launch_bounds__(256) void init_cnt(unsigned* __restrict__ c) {
  int i = blockIdx.x * 256 + threadIdx.x;
  if (i < 1024) st32a(c + i, 0u);
}

// 256 blocks = (bt=blk&15, ht=blk>>4), 384 thr = 6 waves = (layer, gate).
// Each wave holds its gate's weight slice in VGPRs (16 frags = 64 VGPR —
// the residency-safe size, cf. R3). Coalesced sc1 staging into parity-
// double-buffered LDS tiles; gates recombine via LDS gt; publish by wave0
// (h1) / wave3 (h2) as packed 4x-bf16 u64 sc1 stores; R7's proven counter
// sync (publish -> s_waitcnt(0) drain -> inc; consumers spin).
__global__ __launch_bounds__(384, 1) void gru_gate(
    const short* __restrict__ xb, const short* __restrict__ wb,
    const float* __restrict__ bih0, const float* __restrict__ bhh0,
    const float* __restrict__ bih1, const float* __restrict__ bhh1,
    const float* __restrict__ Wfc, const float* __restrict__ bfc,
    unsigned* __restrict__ h1g, unsigned* __restrict__ h2g,
    unsigned* __restrict__ cnt, float* __restrict__ out) {
  const int tid = threadIdx.x;
  const int lane = tid & 63;
  const int w = tid >> 6;
  const int quad = lane >> 4;
  const int col = lane & 15;
  const int bt = blockIdx.x & 15;
  const int ht = blockIdx.x >> 4;
  const int layer = w / 3, gate = w % 3;
  const int jc = ht * 16 + col;

  // [tile: 0=h1prev 1=h2prev 2=x][parity][16 rows * RS shorts]
  __shared__ __align__(16) short sT[3][2][16 * RS];
  __shared__ __align__(16) float gtI[6][16][20];
  __shared__ __align__(16) float gtH[6][16][20];

  unsigned* c0 = cnt + bt * 32;
  unsigned* c1 = cnt + 512 + bt * 32;

  // ---- weights -> VGPRs: 16 frags/lane (64 VGPR) ----
  const short* wih = wb + (layer ? OFF_WIH1 : OFF_WIH0);
  const short* whh = wb + (layer ? OFF_WHH1 : OFF_WHH0);
  const int KIs = layer ? HH : II;
  short8 wfI[8], wfH[8];
#pragma unroll
  for (int f = 0; f < 4; ++f)
    wfI[f] = *(const short8*)(wih + (gate * HH + jc) * KIs + f * 32 + quad * 8);
#pragma unroll
  for (int f = 4; f < 8; ++f)
    wfI[f] = layer ? *(const short8*)(wih + (gate * HH + jc) * KIs + f * 32 + quad * 8)
                   : short8{0, 0, 0, 0, 0, 0, 0, 0};
#pragma unroll
  for (int f = 0; f < 8; ++f)
    wfH[f] = *(const short8*)(whh + (gate * HH + jc) * HH + f * 32 + quad * 8);

  const float* bihL = layer ? bih1 : bih0;
  const float* bhhL = layer ? bhh1 : bhh0;
  float bI, bH;
  if (gate == 2) { bI = bihL[2 * HH + jc]; bH = bhhL[2 * HH + jc]; }
  else { bI = bihL[gate * HH + jc] + bhhL[gate * HH + jc]; bH = 0.f; }

  // elementwise role (wave0: h1 state, wave3: h2 state): 4 cols/thread
  const int erow = lane >> 2;
  const int ec = (lane & 3) * 4;
  float hm[4] = {0.f, 0.f, 0.f, 0.f};

#pragma unroll 1
  for (int p = 0; p <= TT; ++p) {
    const int par = p & 1;
    if (p > 0) {
      if (lane == 0) spin_ge(c0, 16u * (unsigned)p);
      else if (lane == 1) spin_ge(c1, 16u * (unsigned)p);
    }

    // ---- coalesced staging into parity buffers ----
    if (w < 2) {  // h1[p-1] -> sT[0][par]
      if (p > 0) {
        const u64* src = (const u64*)h1g + (size_t)((p + 1) & 1) * HPAR_Q + bt * 1024;
        u64* dst = (u64*)&sT[0][par][0];
#pragma unroll
        for (int k = 0; k < 8; ++k) {
          int q = tid + 128 * k;
          dst[(q >> 6) * RSQ + (q & 63)] = ld64(src + q);
        }
      }
    } else if (w < 4) {  // h2[p-2] -> sT[1][par]
      if (p > 1) {
        const u64* src = (const u64*)h2g + (size_t)par * HPAR_Q + bt * 1024;
        u64* dst = (u64*)&sT[1][par][0];
        int t = tid - 128;
#pragma unroll
        for (int k = 0; k < 8; ++k) {
          int q = t + 128 * k;
          dst[(q >> 6) * RSQ + (q & 63)] = ld64(src + q);
        }
      }
    } else {  // x[p] -> sT[2][par] (plain cached loads)
      if (p < TT) {
        const u64* src = (const u64*)xb + ((size_t)p * BB + bt * 16) * (II / 4);
        u64* dst = (u64*)&sT[2][par][0];
        int t = tid - 256;
#pragma unroll
        for (int k = 0; k < 4; ++k) {
          int q = t + 128 * k;
          dst[(q >> 5) * RSQ + (q & 31)] = src[q];
        }
      }
    }
    __syncthreads();  // bar1: staging visible

    // ---- MFMA: this wave's gate, both mats ----
    const short* tI = layer ? &sT[0][par][0] : &sT[2][par][0];
    const short* tH = layer ? &sT[1][par][0] : &sT[0][par][0];
    const bool doI = layer ? (p >= 1) : (p < TT);
    const bool doH = layer ? (p >= 2) : (p >= 1);
    floatx4 aI = floatx4{bI, bI, bI, bI};
    floatx4 aH = floatx4{bH, bH, bH, bH};
    if (doI) {
      const short* base = tI + col * RS + quad * 8;
#pragma unroll
      for (int f = 0; f < 4; ++f)
        aI = __builtin_amdgcn_mfma_f32_16x16x32_bf16(*(const short8*)(base + f * 32),
                                                     wfI[f], aI, 0, 0, 0);
      if (layer) {
#pragma unroll
        for (int f = 4; f < 8; ++f)
          aI = __builtin_amdgcn_mfma_f32_16x16x32_bf16(*(const short8*)(base + f * 32),
                                                       wfI[f], aI, 0, 0, 0);
      }
    }
    if (doH) {
      const short* base = tH + col * RS + quad * 8;
#pragma unroll
      for (int f = 0; f < 8; ++f)
        aH = __builtin_amdgcn_mfma_f32_16x16x32_bf16(*(const short8*)(base + f * 32),
                                                     wfH[f], aH, 0, 0, 0);
    }
#pragma unroll
    for (int i = 0; i < 4; ++i) {
      gtI[w][quad * 4 + i][col] = aI[i];
      gtH[w][quad * 4 + i][col] = aH[i];
    }
    __syncthreads();  // bar2: gt visible

    // ---- elementwise + publish + drain + inc (wave0: L0, wave3: L1) ----
    if (w == 0) {
      if (p < TT) {
        fvec4 vRI = *(const fvec4*)&gtI[0][erow][ec];
        fvec4 vRH = *(const fvec4*)&gtH[0][erow][ec];
        fvec4 vZI = *(const fvec4*)&gtI[1][erow][ec];
        fvec4 vZH = *(const fvec4*)&gtH[1][erow][ec];
        fvec4 vNI = *(const fvec4*)&gtI[2][erow][ec];
        fvec4 vNH = *(const fvec4*)&gtH[2][erow][ec];
        u64 pack = 0;
#pragma unroll
        for (int c = 0; c < 4; ++c) {
          float r = fast_sigmoid(vRI[c] + vRH[c]);
          float z = fast_sigmoid(vZI[c] + vZH[c]);
          float n = fast_tanh(vNI[c] + r * vNH[c]);
          float h = n + z * (hm[c] - n);
          hm[c] = h;
          pack |= (u64)(unsigned short)f2bf(h) << (16 * c);
        }
        st64((u64*)h1g + (size_t)par * HPAR_Q + (bt * 16 + erow) * 64 + ht * 4 +
                 (lane & 3),
             pack);
      }
      drain_then();
      if (lane == 0)
        __hip_atomic_fetch_add(c0, 1u, __ATOMIC_RELAXED, __HIP_MEMORY_SCOPE_AGENT);
    } else if (w == 3) {
      if (p >= 1) {
        fvec4 vRI = *(const fvec4*)&gtI[3][erow][ec];
        fvec4 vRH = *(const fvec4*)&gtH[3][erow][ec];
        fvec4 vZI = *(const fvec4*)&gtI[4][erow][ec];
        fvec4 vZH = *(const fvec4*)&gtH[4][erow][ec];
        fvec4 vNI = *(const fvec4*)&gtI[5][erow][ec];
        fvec4 vNH = *(const fvec4*)&gtH[5][erow][ec];
        u64 pack = 0;
#pragma unroll
        for (int c = 0; c < 4; ++c) {
          float r = fast_sigmoid(vRI[c] + vRH[c]);
          float z = fast_sigmoid(vZI[c] + vZH[c]);
          float n = fast_tanh(vNI[c] + r * vNH[c]);
          float h = n + z * (hm[c] - n);
          hm[c] = h;
          pack |= (u64)(unsigned short)f2bf(h) << (16 * c);
        }
        st64((u64*)h2g + (size_t)((p + 1) & 1) * HPAR_Q + (bt * 16 + erow) * 64 +
                 ht * 4 + (lane & 3),
             pack);
      }
      drain_then();
      if (lane == 0)
        __hip_atomic_fetch_add(c1, 1u, __ATOMIC_RELAXED, __HIP_MEMORY_SCOPE_AGENT);
    }
    // no bar3: LDS tiles are parity-double-buffered; gt protected by next bar1+bar2
  }

  // ---- FC epilogue: out = h2[511] @ Wfc^T + bfc ----
  if (lane == 0) spin_ge(c1, 16u * (unsigned)(TT + 1));
  if (tid < 128) {  // stage h2[511] (global parity 1) -> sT[1][1]
    const u64* src = (const u64*)h2g + (size_t)1 * HPAR_Q + bt * 1024;
    u64* dst = (u64*)&sT[1][1][0];
#pragma unroll
    for (int k = 0; k < 8; ++k) {
      int q = tid + 128 * k;
      dst[(q >> 6) * RSQ + (q & 63)] = ld64(src + q);
    }
  }
  __syncthreads();
  if (w == 0) {
    float bv = bfc[jc];
    floatx4 acc = floatx4{bv, bv, bv, bv};
    const short* base = &sT[1][1][0] + col * RS + quad * 8;
#pragma unroll
    for (int f = 0; f < 8; ++f) {
      short8 a = *(const short8*)(base + f * 32);
      short8 bw = cvt8(Wfc + jc * HH + f * 32 + quad * 8);
      acc = __builtin_amdgcn_mfma_f32_16x16x32_bf16(a, bw, acc, 0, 0, 0);
    }
#pragma unroll
    for (int i = 0; i < 4; ++i)
      out[(size_t)(bt * 16 + quad * 4 + i) * HH + jc] = acc[i];
  }
}

extern "C" void kernel_launch(void* const* d_in, const int* in_sizes, int n_in,
                              void* d_out, int out_size, void* d_ws,
                              size_t ws_size, hipStream_t stream) {
  const float* x = (const float*)d_in[0];
  const float* Wih0 = (const float*)d_in[1];
  const float* Whh0 = (const float*)d_in[2];
  const float* bih0 = (const float*)d_in[3];
  const float* bhh0 = (const float*)d_in[4];
  const float* Wih1 = (const float*)d_in[5];
  const float* Whh1 = (const float*)d_in[6];
  const float* bih1 = (const float*)d_in[7];
  const float* bhh1 = (const float*)d_in[8];
  const float* Wfc = (const float*)d_in[9];
  const float* bfc = (const float*)d_in[10];

  unsigned* h1g = (unsigned*)d_ws;
  unsigned* h2g = h1g + HBUF_U32;
  short* wb = (short*)(h2g + HBUF_U32);
  short* xbuf = wb + W_TOTAL;
  unsigned* cnt = (unsigned*)(xbuf + XB_ELEMS);

  cvt_weights<<<(W_TOTAL + 255) / 256, 256, 0, stream>>>(Wih0, Whh0, Wih1, Whh1, wb);
  cvt_x<<<(int)((XB_ELEMS / 8 + 255) / 256), 256, 0, stream>>>(x, xbuf);
  init_cnt<<<4, 256, 0, stream>>>(cnt);
  gru_gate<<<256, 384, 0, stream>>>(xbuf, wb, bih0, bhh0, bih1, bhh1, Wfc, bfc,
                                    h1g, h2g, cnt, (float*)d_out);
}

// Round 9
// 3705.764 us; speedup vs baseline: 1.2500x; 1.2500x over previous
//
#include <hip/hip_runtime.h>

#define TT 512
#define BB 256
#define II 128
#define HH 256
#define RS 260   // LDS tile row stride, shorts: (2c+4q) mod 32 -> <=2-way, free
#define RSQ 65   // RS/4, u64 stride

typedef __attribute__((ext_vector_type(8))) short short8;
typedef __attribute__((ext_vector_type(4))) float floatx4;
typedef __attribute__((ext_vector_type(4))) float fvec4;
typedef unsigned long long u64;

// ws layout: h1g u32[2][BB][HH/2] | h2g same | wb bf16 | xb bf16 | cnt u32[1024]
#define HBUF_U32 (2 * BB * (HH / 2))
#define HPAR_Q (BB * HH / 4)  // u64 per parity buffer
#define OFF_WIH0 0
#define OFF_WHH0 (OFF_WIH0 + 3 * HH * II)
#define OFF_WIH1 (OFF_WHH0 + 3 * HH * HH)
#define OFF_WHH1 (OFF_WIH1 + 3 * HH * HH)
#define W_TOTAL (OFF_WHH1 + 3 * HH * HH)
#define XB_ELEMS ((size_t)TT * BB * II)

#define PIN(v) asm volatile("" : "+v"(v))

__device__ __forceinline__ short f2bf(float f) {
  unsigned u = __builtin_bit_cast(unsigned, f);
  u = u + 0x7fffu + ((u >> 16) & 1u);
  return (short)(u >> 16);
}
__device__ __forceinline__ float fast_sigmoid(float x) {
  return __fdividef(1.0f, 1.0f + __expf(-x));
}
__device__ __forceinline__ float fast_tanh(float x) {
  return 1.0f - __fdividef(2.0f, 1.0f + __expf(2.0f * x));
}
__device__ __forceinline__ short8 cvt8(const float* __restrict__ p) {
  fvec4 lo = *(const fvec4*)p;
  fvec4 hi = *(const fvec4*)(p + 4);
  short8 r;
  r[0] = f2bf(lo[0]); r[1] = f2bf(lo[1]); r[2] = f2bf(lo[2]); r[3] = f2bf(lo[3]);
  r[4] = f2bf(hi[0]); r[5] = f2bf(hi[1]); r[6] = f2bf(hi[2]); r[7] = f2bf(hi[3]);
  return r;
}
__device__ __forceinline__ u64 ld64(const u64* p) {
  return __hip_atomic_load(p, __ATOMIC_RELAXED, __HIP_MEMORY_SCOPE_AGENT);
}
__device__ __forceinline__ void st32a(unsigned* p, unsigned v) {
  __hip_atomic_store(p, v, __ATOMIC_RELAXED, __HIP_MEMORY_SCOPE_AGENT);
}
__device__ __forceinline__ void spin_ge(const unsigned* c, unsigned tgt) {
  int g = 0;
  while (__hip_atomic_load(c, __ATOMIC_RELAXED, __HIP_MEMORY_SCOPE_AGENT) < tgt &&
         g < (1 << 22))
    ++g;
}
__device__ __forceinline__ void drain_then(void) {
  __atomic_signal_fence(__ATOMIC_SEQ_CST);
  __builtin_amdgcn_s_waitcnt(0);
  __atomic_signal_fence(__ATOMIC_SEQ_CST);
}

__global__ __launch_bounds__(256) void cvt_weights(
    const float* __restrict__ w0, const float* __restrict__ w1,
    const float* __restrict__ w2, const float* __restrict__ w3,
    short* __restrict__ out) {
  int i = blockIdx.x * 256 + threadIdx.x;
  if (i >= W_TOTAL) return;
  float v;
  if (i < OFF_WHH0)      v = w0[i - OFF_WIH0];
  else if (i < OFF_WIH1) v = w1[i - OFF_WHH0];
  else if (i < OFF_WHH1) v = w2[i - OFF_WIH1];
  else                   v = w3[i - OFF_WHH1];
  out[i] = f2bf(v);
}

__global__ __launch_bounds__(256) void cvt_x(const float* __restrict__ x,
                                             short* __restrict__ xb) {
  size_t i = ((size_t)blockIdx.x * 256 + threadIdx.x) * 8;
  if (i >= XB_ELEMS) return;
#pragma unroll
  for (int k = 0; k < 8; ++k) xb[i + k] = f2bf(x[i + k]);
}

__global__ __launch_bounds__(256) void init_cnt(unsigned* __restrict__ c) {
  int i = blockIdx.x * 256 + threadIdx.x;
  if (i < 1024) st32a(c + i, 0u);
}

// 256 blocks = (bt=blk&15, ht=blk>>4), 128 thr = 2 waves.
// w0 = layer 0, w1 = layer 1; each owns cols [ht*16,+16), all 3 gates in
// accumulators (identical lane layout -> in-register elementwise, no gt LDS).
// Weights are loaded ONCE and asm-pinned into VGPRs (blocks rematerialization
// -- the R3..R8 hidden cost). Coalesced tile staging (one wave = one tile,
// 512B/instr) into parity-double-buffered LDS. R4/R7 proven sync: publish
// (sc1) -> s_waitcnt(0) drain -> per-(bt,layer) counter inc; consumer spins.
// Phase p: w0 computes h1[p], w1 computes h2[p-1]; phases 0/1 skip h reads.
__global__ __launch_bounds__(128, 1) void gru_pin(
    const short* __restrict__ xb, const short* __restrict__ wb,
    const float* __restrict__ bih0, const float* __restrict__ bhh0,
    const float* __restrict__ bih1, const float* __restrict__ bhh1,
    const float* __restrict__ Wfc, const float* __restrict__ bfc,
    unsigned* __restrict__ h1g, unsigned* __restrict__ h2g,
    unsigned* __restrict__ cnt, float* __restrict__ out) {
  const int tid = threadIdx.x;
  const int lane = tid & 63;
  const int w = tid >> 6;
  const int quad = lane >> 4;
  const int col = lane & 15;
  const int bt = blockIdx.x & 15;
  const int ht = blockIdx.x >> 4;
  const int jc = ht * 16 + col;

  // [tile: 0=h1prev, 1=h2prev][parity][16 rows * RS shorts]
  __shared__ __align__(16) short sT[2][2][16 * RS];

  unsigned* c0 = cnt + bt * 32;
  unsigned* c1 = cnt + 512 + bt * 32;

  float hm[4] = {0.f, 0.f, 0.f, 0.f};

  if (w == 0) {
    // ---- L0 weights -> VGPRs, pinned (12 + 24 frags = 144 VGPR) ----
    short8 wI[3][4], wH[3][8];
#pragma unroll
    for (int g = 0; g < 3; ++g) {
#pragma unroll
      for (int f = 0; f < 4; ++f) {
        wI[g][f] = *(const short8*)(wb + OFF_WIH0 + (g * HH + jc) * II + f * 32 + quad * 8);
        PIN(wI[g][f]);
      }
#pragma unroll
      for (int f = 0; f < 8; ++f) {
        wH[g][f] = *(const short8*)(wb + OFF_WHH0 + (g * HH + jc) * HH + f * 32 + quad * 8);
        PIN(wH[g][f]);
      }
    }
    const float bR = bih0[jc] + bhh0[jc];
    const float bZ = bih0[HH + jc] + bhh0[HH + jc];
    const float bNI = bih0[2 * HH + jc];
    const float bNH = bhh0[2 * HH + jc];

#pragma unroll 1
    for (int p = 0; p <= TT; ++p) {
      const int par = p & 1;
      short8 ax[4];
      if (p < TT) {
        const short* xr = xb + ((size_t)p * BB + bt * 16 + col) * II + quad * 8;
#pragma unroll
        for (int f = 0; f < 4; ++f) ax[f] = *(const short8*)(xr + f * 32);
      }
      if (p > 0) {
        if (lane == 0) spin_ge(c0, 16u * (unsigned)p);
        // stage h1[p-1] tile: instruction k loads row k (contiguous 512B)
        const u64* src = (const u64*)h1g + (size_t)((p + 1) & 1) * HPAR_Q + bt * 1024;
        u64* dst = (u64*)&sT[0][par][0];
#pragma unroll
        for (int k = 0; k < 16; ++k) dst[k * RSQ + lane] = ld64(src + k * 64 + lane);
      }
      __syncthreads();

      if (p < TT) {
        floatx4 aR = floatx4{bR, bR, bR, bR};
        floatx4 aZ = floatx4{bZ, bZ, bZ, bZ};
        floatx4 aNI = floatx4{bNI, bNI, bNI, bNI};
        floatx4 aNH = floatx4{bNH, bNH, bNH, bNH};
#pragma unroll
        for (int f = 0; f < 4; ++f) {
          aR = __builtin_amdgcn_mfma_f32_16x16x32_bf16(ax[f], wI[0][f], aR, 0, 0, 0);
          aZ = __builtin_amdgcn_mfma_f32_16x16x32_bf16(ax[f], wI[1][f], aZ, 0, 0, 0);
          aNI = __builtin_amdgcn_mfma_f32_16x16x32_bf16(ax[f], wI[2][f], aNI, 0, 0, 0);
        }
        if (p > 0) {
          const short* hA = &sT[0][par][0] + col * RS + quad * 8;
#pragma unroll
          for (int f = 0; f < 8; ++f) {
            short8 a = *(const short8*)(hA + f * 32);
            aR = __builtin_amdgcn_mfma_f32_16x16x32_bf16(a, wH[0][f], aR, 0, 0, 0);
            aZ = __builtin_amdgcn_mfma_f32_16x16x32_bf16(a, wH[1][f], aZ, 0, 0, 0);
            aNH = __builtin_amdgcn_mfma_f32_16x16x32_bf16(a, wH[2][f], aNH, 0, 0, 0);
          }
        }
        unsigned* dst = h1g + (size_t)par * (BB * HH / 2);
#pragma unroll
        for (int i = 0; i < 4; ++i) {
          float r = fast_sigmoid(aR[i]);
          float z = fast_sigmoid(aZ[i]);
          float n = fast_tanh(aNI[i] + r * aNH[i]);
          float h = n + z * (hm[i] - n);
          hm[i] = h;
          unsigned hv = (unsigned)(unsigned short)f2bf(h);
          unsigned ov = (unsigned)__builtin_amdgcn_ds_swizzle((int)hv, 0x041F);
          if (!(lane & 1))
            st32a(dst + (bt * 16 + quad * 4 + i) * (HH / 2) + (jc >> 1),
                  hv | (ov << 16));
        }
      }
      drain_then();
      if (lane == 0)
        __hip_atomic_fetch_add(c0, 1u, __ATOMIC_RELAXED, __HIP_MEMORY_SCOPE_AGENT);
    }
  } else {
    // ---- L1 weights -> VGPRs, pinned (48 frags = 192 VGPR) ----
    short8 wI[3][8], wH[3][8];
#pragma unroll
    for (int g = 0; g < 3; ++g) {
#pragma unroll
      for (int f = 0; f < 8; ++f) {
        wI[g][f] = *(const short8*)(wb + OFF_WIH1 + (g * HH + jc) * HH + f * 32 + quad * 8);
        PIN(wI[g][f]);
        wH[g][f] = *(const short8*)(wb + OFF_WHH1 + (g * HH + jc) * HH + f * 32 + quad * 8);
        PIN(wH[g][f]);
      }
    }
    const float bR = bih1[jc] + bhh1[jc];
    const float bZ = bih1[HH + jc] + bhh1[HH + jc];
    const float bNI = bih1[2 * HH + jc];
    const float bNH = bhh1[2 * HH + jc];

#pragma unroll 1
    for (int p = 0; p <= TT; ++p) {
      const int par = p & 1;
      if (p > 0) {
        if (lane == 0) spin_ge(c1, 16u * (unsigned)p);
        if (p > 1) {
          // stage h2[p-2] tile (parity p&1)
          const u64* src = (const u64*)h2g + (size_t)par * HPAR_Q + bt * 1024;
          u64* dst = (u64*)&sT[1][par][0];
#pragma unroll
          for (int k = 0; k < 16; ++k) dst[k * RSQ + lane] = ld64(src + k * 64 + lane);
        }
      }
      __syncthreads();

      if (p > 0) {
        floatx4 aR = floatx4{bR, bR, bR, bR};
        floatx4 aZ = floatx4{bZ, bZ, bZ, bZ};
        floatx4 aNI = floatx4{bNI, bNI, bNI, bNI};
        floatx4 aNH = floatx4{bNH, bNH, bNH, bNH};
        const short* h1A = &sT[0][par][0] + col * RS + quad * 8;  // h1[p-1] (staged by w0)
#pragma unroll
        for (int f = 0; f < 8; ++f) {
          short8 a = *(const short8*)(h1A + f * 32);
          aR = __builtin_amdgcn_mfma_f32_16x16x32_bf16(a, wI[0][f], aR, 0, 0, 0);
          aZ = __builtin_amdgcn_mfma_f32_16x16x32_bf16(a, wI[1][f], aZ, 0, 0, 0);
          aNI = __builtin_amdgcn_mfma_f32_16x16x32_bf16(a, wI[2][f], aNI, 0, 0, 0);
        }
        if (p > 1) {
          const short* h2A = &sT[1][par][0] + col * RS + quad * 8;  // h2[p-2]
#pragma unroll
          for (int f = 0; f < 8; ++f) {
            short8 a = *(const short8*)(h2A + f * 32);
            aR = __builtin_amdgcn_mfma_f32_16x16x32_bf16(a, wH[0][f], aR, 0, 0, 0);
            aZ = __builtin_amdgcn_mfma_f32_16x16x32_bf16(a, wH[1][f], aZ, 0, 0, 0);
            aNH = __builtin_amdgcn_mfma_f32_16x16x32_bf16(a, wH[2][f], aNH, 0, 0, 0);
          }
        }
        unsigned* dst = h2g + (size_t)((p + 1) & 1) * (BB * HH / 2);
#pragma unroll
        for (int i = 0; i < 4; ++i) {
          float r = fast_sigmoid(aR[i]);
          float z = fast_sigmoid(aZ[i]);
          float n = fast_tanh(aNI[i] + r * aNH[i]);
          float h = n + z * (hm[i] - n);
          hm[i] = h;
          unsigned hv = (unsigned)(unsigned short)f2bf(h);
          unsigned ov = (unsigned)__builtin_amdgcn_ds_swizzle((int)hv, 0x041F);
          if (!(lane & 1))
            st32a(dst + (bt * 16 + quad * 4 + i) * (HH / 2) + (jc >> 1),
                  hv | (ov << 16));
        }
      }
      drain_then();
      if (lane == 0)
        __hip_atomic_fetch_add(c1, 1u, __ATOMIC_RELAXED, __HIP_MEMORY_SCOPE_AGENT);
    }
  }

  // ---- FC epilogue: out = h2[511] @ Wfc^T + bfc ----
  if (w == 0 && lane == 0) spin_ge(c1, 16u * (unsigned)(TT + 1));
  __syncthreads();  // all lanes held until c1 target reached
  {
    // both waves stage h2[511] (parity 1) into sT[1][1], coalesced
    const u64* src = (const u64*)h2g + (size_t)1 * HPAR_Q + bt * 1024;
    u64* dst = (u64*)&sT[1][1][0];
#pragma unroll
    for (int k = 0; k < 8; ++k) {
      int q = tid + 128 * k;
      dst[(q >> 6) * RSQ + (q & 63)] = ld64(src + q);
    }
  }
  __syncthreads();
  if (w == 0) {
    float bv = bfc[jc];
    floatx4 acc = floatx4{bv, bv, bv, bv};
    const short* base = &sT[1][1][0] + col * RS + quad * 8;
#pragma unroll
    for (int f = 0; f < 8; ++f) {
      short8 a = *(const short8*)(base + f * 32);
      short8 bw = cvt8(Wfc + jc * HH + f * 32 + quad * 8);
      acc = __builtin_amdgcn_mfma_f32_16x16x32_bf16(a, bw, acc, 0, 0, 0);
    }
#pragma unroll
    for (int i = 0; i < 4; ++i)
      out[(size_t)(bt * 16 + quad * 4 + i) * HH + jc] = acc[i];
  }
}

extern "C" void kernel_launch(void* const* d_in, const int* in_sizes, int n_in,
                              void* d_out, int out_size, void* d_ws,
                              size_t ws_size, hipStream_t stream) {
  const float* x = (const float*)d_in[0];
  const float* Wih0 = (const float*)d_in[1];
  const float* Whh0 = (const float*)d_in[2];
  const float* bih0 = (const float*)d_in[3];
  const float* bhh0 = (const float*)d_in[4];
  const float* Wih1 = (const float*)d_in[5];
  const float* Whh1 = (const float*)d_in[6];
  const float* bih1 = (const float*)d_in[7];
  const float* bhh1 = (const float*)d_in[8];
  const float* Wfc = (const float*)d_in[9];
  const float* bfc = (const float*)d_in[10];

  unsigned* h1g = (unsigned*)d_ws;
  unsigned* h2g = h1g + HBUF_U32;
  short* wb = (short*)(h2g + HBUF_U32);
  short* xbuf = wb + W_TOTAL;
  unsigned* cnt = (unsigned*)(xbuf + XB_ELEMS);

  cvt_weights<<<(W_TOTAL + 255) / 256, 256, 0, stream>>>(Wih0, Whh0, Wih1, Whh1, wb);
  cvt_x<<<(int)((XB_ELEMS / 8 + 255) / 256), 256, 0, stream>>>(x, xbuf);
  init_cnt<<<4, 256, 0, stream>>>(cnt);
  gru_pin<<<256, 128, 0, stream>>>(xbuf, wb, bih0, bhh0, bih1, bhh1, Wfc, bfc,
                                   h1g, h2g, cnt, (float*)d_out);
}